// Round 5
// baseline (168.381 us; speedup 1.0000x reference)
//
#include <hip/hip_runtime.h>
#include <hip/hip_bf16.h>

typedef _Float16 h8 __attribute__((ext_vector_type(8)));
typedef _Float16 h2 __attribute__((ext_vector_type(2)));
typedef float f2 __attribute__((ext_vector_type(2)));
typedef float f4 __attribute__((ext_vector_type(4)));
typedef float f16v __attribute__((ext_vector_type(16)));

#define MFMA16(a, b, c) __builtin_amdgcn_mfma_f32_16x16x32_f16(a, b, c, 0, 0, 0)
#define MFMA32(a, b, c) __builtin_amdgcn_mfma_f32_32x32x16_f16(a, b, c, 0, 0, 0)

static constexpr int DM = 512;   // d_model
static constexpr int SL = 4096;  // seq len
static constexpr int NH = 8;     // heads
static constexpr int DK = 64;    // head dim
static constexpr int NB = 2;     // batch

// ---------------------------------------------------------------------------
// Kernel 1: fused Q/K/V projections.  out = X @ W^T + b, cast to fp16.
// 1D grid, XCD-swizzled so the 8 N-tiles of one (proj, M-panel) share an XCD
// (A-panel becomes L2-resident after the first reader).  K-step 64.
// ---------------------------------------------------------------------------
__global__ __launch_bounds__(256) void proj_qkv_kernel(
    const float* __restrict__ Qin, const float* __restrict__ Kin,
    const float* __restrict__ Vin,
    const float* __restrict__ Wq, const float* __restrict__ Wk,
    const float* __restrict__ Wv,
    const float* __restrict__ bq, const float* __restrict__ bk,
    const float* __restrict__ bv,
    _Float16* __restrict__ qo, _Float16* __restrict__ ko,
    _Float16* __restrict__ vTo)
{
    // swizzle: 3072 blocks = 8 XCD * 384; orig layout (proj*128 + m)*8 + n
    const int bid = blockIdx.x;
    const int op  = (bid & 7) * 384 + (bid >> 3);
    const int ntile = op & 7;
    const int mp    = op >> 3;
    const int mt    = mp & 127;
    const int which = mp >> 7;

    const float* __restrict__ X    = which == 0 ? Qin : (which == 1 ? Kin : Vin);
    const float* __restrict__ W    = which == 0 ? Wq  : (which == 1 ? Wk  : Wv);
    const float* __restrict__ bias = which == 0 ? bq  : (which == 1 ? bk  : bv);

    __shared__ _Float16 At[64][72];   // 64 rows x 64 k (+8 pad)
    __shared__ _Float16 Bt[64][72];

    const int t = threadIdx.x;
    const int w = t >> 6;
    const int l = t & 63;
    const int mbase = mt * 64;
    const int nbase = ntile * 64;
    const int wm = (w >> 1) * 32;
    const int wn = (w & 1) * 32;
    const int fr = l & 15;
    const int gk = (l >> 4) * 8;

    const int srow = t >> 2;        // 0..63
    const int skol = (t & 3) * 16;  // 0,16,32,48

    f4 acc[2][2] = {};

    for (int kk = 0; kk < DM; kk += 64) {
        __syncthreads();
        {
            const float* ap = X + (size_t)(mbase + srow) * DM + kk + skol;
            float4 a0 = *(const float4*)ap;
            float4 a1 = *(const float4*)(ap + 4);
            float4 a2 = *(const float4*)(ap + 8);
            float4 a3 = *(const float4*)(ap + 12);
            h8 av0, av1;
            av0[0] = (_Float16)a0.x; av0[1] = (_Float16)a0.y;
            av0[2] = (_Float16)a0.z; av0[3] = (_Float16)a0.w;
            av0[4] = (_Float16)a1.x; av0[5] = (_Float16)a1.y;
            av0[6] = (_Float16)a1.z; av0[7] = (_Float16)a1.w;
            av1[0] = (_Float16)a2.x; av1[1] = (_Float16)a2.y;
            av1[2] = (_Float16)a2.z; av1[3] = (_Float16)a2.w;
            av1[4] = (_Float16)a3.x; av1[5] = (_Float16)a3.y;
            av1[6] = (_Float16)a3.z; av1[7] = (_Float16)a3.w;
            *(h8*)&At[srow][skol]     = av0;
            *(h8*)&At[srow][skol + 8] = av1;

            const float* bp = W + (size_t)(nbase + srow) * DM + kk + skol;
            float4 b0 = *(const float4*)bp;
            float4 b1 = *(const float4*)(bp + 4);
            float4 b2 = *(const float4*)(bp + 8);
            float4 b3 = *(const float4*)(bp + 12);
            h8 bw0, bw1;
            bw0[0] = (_Float16)b0.x; bw0[1] = (_Float16)b0.y;
            bw0[2] = (_Float16)b0.z; bw0[3] = (_Float16)b0.w;
            bw0[4] = (_Float16)b1.x; bw0[5] = (_Float16)b1.y;
            bw0[6] = (_Float16)b1.z; bw0[7] = (_Float16)b1.w;
            bw1[0] = (_Float16)b2.x; bw1[1] = (_Float16)b2.y;
            bw1[2] = (_Float16)b2.z; bw1[3] = (_Float16)b2.w;
            bw1[4] = (_Float16)b3.x; bw1[5] = (_Float16)b3.y;
            bw1[6] = (_Float16)b3.z; bw1[7] = (_Float16)b3.w;
            *(h8*)&Bt[srow][skol]     = bw0;
            *(h8*)&Bt[srow][skol + 8] = bw1;
        }
        __syncthreads();

#pragma unroll
        for (int k2 = 0; k2 < 2; ++k2) {
            h8 af[2], bf[2];
#pragma unroll
            for (int mi = 0; mi < 2; ++mi)
                af[mi] = *(const h8*)&At[wm + mi * 16 + fr][k2 * 32 + gk];
#pragma unroll
            for (int ni = 0; ni < 2; ++ni)
                bf[ni] = *(const h8*)&Bt[wn + ni * 16 + fr][k2 * 32 + gk];
#pragma unroll
            for (int mi = 0; mi < 2; ++mi)
#pragma unroll
                for (int ni = 0; ni < 2; ++ni)
                    acc[mi][ni] = MFMA16(af[mi], bf[ni], acc[mi][ni]);
        }
    }

#pragma unroll
    for (int ni = 0; ni < 2; ++ni) {
        const int n = nbase + wn + ni * 16 + fr;
        const float bb = bias[n];
        const int hh = n >> 6;
        const int d  = n & 63;
#pragma unroll
        for (int mi = 0; mi < 2; ++mi) {
#pragma unroll
            for (int r = 0; r < 4; ++r) {
                const int m = mbase + wm + mi * 16 + (l >> 4) * 4 + r;
                const int bi = m >> 12;
                const int s  = m & 4095;
                const float val = acc[mi][ni][r] + bb;
                if (which == 2) {
                    vTo[((size_t)(bi * NH + hh) * DK + d) * SL + s] = (_Float16)val;
                } else {
                    _Float16* dst = (which == 0) ? qo : ko;
                    dst[((size_t)(bi * NH + hh) * SL + s) * DK + d] = (_Float16)val;
                }
            }
        }
    }
}

// ---------------------------------------------------------------------------
// Kernel 2: flash attention, 32x32x16 MFMA, P entirely in registers.
//  - bias C-init loaded as uniform ds_read_b64 (b128 broadcast suspect)
//  - s_setprio around MFMA clusters
// ---------------------------------------------------------------------------
static constexpr int NT   = SL / 64;   // 64 K-tiles
static constexpr int QBLK = 128;

__device__ __forceinline__ void stage_tiles(
    _Float16* Ktb, _Float16* Vtb,
    const _Float16* kbh, const _Float16* vbh, int kb, int t)
{
    const int w = t >> 6, l = t & 63;
    const char* ksrc = (const char*)(kbh + (size_t)kb * DK);  // contiguous 8KB
#pragma unroll
    for (int s2 = 0; s2 < 2; ++s2) {
        const int c  = s2 * 256 + w * 64 + l;   // dest 16B chunk 0..511
        const int kr = c >> 3;                  // dest row (staged key index)
        const int sl = c & 7;                   // dest chunk slot in row
        // source row: swap bits 2<->3 of key index (within each 16-key group)
        const int srow = (kr & ~12) | ((kr & 4) << 1) | ((kr & 8) >> 1);
        const int cs = srow * 8 + (sl ^ (kr & 7));   // + XOR bank swizzle
        char* dst = (char*)Ktb + (size_t)(s2 * 4096 + w * 1024);  // wave-uniform
        __builtin_amdgcn_global_load_lds(
            (const __attribute__((address_space(1))) void*)(ksrc + (size_t)cs * 16),
            (__attribute__((address_space(3))) void*)dst, 16, 0, 0);
    }
#pragma unroll
    for (int s2 = 0; s2 < 2; ++s2) {
        const int c  = s2 * 256 + w * 64 + l;
        const int d  = c >> 3;                  // V^T row (d index), unpermuted
        const int cs = (c & 7) ^ (d & 7);       // XOR bank swizzle
        const _Float16* src = vbh + (size_t)d * SL + kb + cs * 8;
        char* dst = (char*)Vtb + (size_t)(s2 * 4096 + w * 1024);
        __builtin_amdgcn_global_load_lds(
            (const __attribute__((address_space(1))) void*)src,
            (__attribute__((address_space(3))) void*)dst, 16, 0, 0);
    }
}

__global__ __launch_bounds__(256) void attn_kernel(
    const _Float16* __restrict__ qg, const _Float16* __restrict__ kg,
    const _Float16* __restrict__ vTg, const int* __restrict__ mask,
    _Float16* __restrict__ comb)
{
    const int t   = threadIdx.x;
    const int w   = t >> 6;
    const int l   = t & 63;
    const int l31 = l & 31;
    const int hi  = l >> 5;
    const int r7  = l31 & 7;
    const int hh  = blockIdx.x & 7;
    const int b   = blockIdx.x >> 3;
    const int qt  = blockIdx.y;

    const _Float16* qbh = qg  + (size_t)(b * NH + hh) * SL * DK;
    const _Float16* kbh = kg  + (size_t)(b * NH + hh) * SL * DK;
    const _Float16* vbh = vTg + (size_t)(b * NH + hh) * DK * SL;
    const int* mrow = mask + b * SL;

    __shared__ __align__(16) _Float16 Kt[2][4096];  // [key 64][d 64], swizzled+row-perm
    __shared__ __align__(16) _Float16 Vt[2][4096];  // [d 64][key 64], swizzled
    __shared__ __align__(16) float bias_tab[SL];    // mask -> {0, -1e38}

    // one-time: mask -> f32 bias table (each thread covers 16 entries)
#pragma unroll
    for (int j = 0; j < 4; ++j) {
        int4 v = *(const int4*)&mrow[t * 16 + j * 4];
        f4 bv;
        bv[0] = v.x ? 0.f : -1e38f; bv[1] = v.y ? 0.f : -1e38f;
        bv[2] = v.z ? 0.f : -1e38f; bv[3] = v.w ? 0.f : -1e38f;
        *(f4*)&bias_tab[t * 16 + j * 4] = bv;
    }

    // Q fragment (QK B-operand), pre-scaled by 1/sqrt(dk) * log2(e)
    const _Float16 sch = (_Float16)(0.125f * 1.44269504089f);
    const h8 sc8 = {sch, sch, sch, sch, sch, sch, sch, sch};
    h8 qf[4];
    {
        const _Float16* qp = qbh + (size_t)(qt * QBLK + w * 32 + l31) * DK + hi * 8;
#pragma unroll
        for (int st = 0; st < 4; ++st)
            qf[st] = *(const h8*)(qp + st * 16) * sc8;
    }

    stage_tiles(Kt[0], Vt[0], kbh, vbh, 0, t);
    __syncthreads();

    f16v ov[2] = {};             // O^T acc: [dsub] 32x32, col q = l31
    float ls0 = 0.f, ls1 = 0.f;  // row-sum partials

    int cur = 0;
    for (int kt = 0; kt < NT; ++kt) {
        const int kb = kt * 64;
        if (kt + 1 < NT)
            stage_tiles(Kt[cur ^ 1], Vt[cur ^ 1], kbh, vbh, kb + 64, t);

        const _Float16* Kc = Kt[cur];
        const _Float16* Vc = Vt[cur];

        // QK acc init = mask bias at permuted key index (uniform b64 reads):
        // acc reg r=4j+c (subtile s): bias idx = kb+32s+16(j>>1)+4(j&1)+8hi+c
        f16v sc[2];
#pragma unroll
        for (int s = 0; s < 2; ++s) {
            union { f2 q[8]; f16v v; } u;
#pragma unroll
            for (int j = 0; j < 4; ++j) {
                const int base = kb + s * 32 + ((j >> 1) << 4) + ((j & 1) << 2) + (hi << 3);
                u.q[2 * j]     = *(const f2*)&bias_tab[base];
                u.q[2 * j + 1] = *(const f2*)&bias_tab[base + 2];
            }
            sc[s] = u.v;
        }

        // S^T = K' . Q^T + bias  (A-frag: lane k'+32hi reads K'[k'][8hi+e])
        __builtin_amdgcn_s_setprio(1);
#pragma unroll
        for (int s = 0; s < 2; ++s) {
            const int rb = (s * 32 + l31) * 64;
#pragma unroll
            for (int st = 0; st < 4; ++st) {
                h8 a = *(const h8*)&Kc[rb + (((st * 2 + hi) ^ r7) << 3)];
                sc[s] = MFMA32(a, qf[st], sc[s]);
            }
        }
        __builtin_amdgcn_s_setprio(0);

        // p = exp2(s) in place; accumulate row-sum
#pragma unroll
        for (int s = 0; s < 2; ++s)
#pragma unroll
            for (int r = 0; r < 16; ++r)
                sc[s][r] = __builtin_amdgcn_exp2f(sc[s][r]);
#pragma unroll
        for (int r = 0; r < 16; ++r) { ls0 += sc[0][r]; ls1 += sc[1][r]; }

        // PV: per 16-key step ks, B-frag = own regs [8κ..8κ+7] packed in order
        __builtin_amdgcn_s_setprio(1);
#pragma unroll
        for (int ks = 0; ks < 4; ++ks) {
            const int s  = ks >> 1;
            const int e0 = (ks & 1) * 8;
            union { h2 h[4]; h8 v; } pf;
#pragma unroll
            for (int u2 = 0; u2 < 4; ++u2)
                pf.h[u2] = __builtin_bit_cast(h2,
                    __builtin_amdgcn_cvt_pkrtz(sc[s][e0 + 2 * u2],
                                               sc[s][e0 + 2 * u2 + 1]));
#pragma unroll
            for (int ds = 0; ds < 2; ++ds) {
                h8 av = *(const h8*)&Vc[(ds * 32 + l31) * 64 +
                                        (((ks * 2 + hi) ^ r7) << 3)];
                ov[ds] = MFMA32(av, pf.v, ov[ds]);
            }
        }
        __builtin_amdgcn_s_setprio(0);

        __syncthreads();
        cur ^= 1;
    }

    // row-sum: own 32 values + partner half -> full sum for column q
    float lsum = ls0 + ls1;
    lsum += __shfl_xor(lsum, 32);
    const float inv = 1.0f / lsum;

    // O^T reg r=4j+c (dsub ds): d = 32ds + 8j + 4hi + c, q = l31
    _Float16* crow = comb + (size_t)(b * SL + qt * QBLK + w * 32 + l31) * DM + hh * DK;
#pragma unroll
    for (int ds = 0; ds < 2; ++ds) {
#pragma unroll
        for (int j = 0; j < 4; ++j) {
            const int d0 = ds * 32 + j * 8 + hi * 4;
            h2 w0 = __builtin_bit_cast(h2,
                __builtin_amdgcn_cvt_pkrtz(ov[ds][4 * j] * inv, ov[ds][4 * j + 1] * inv));
            h2 w1 = __builtin_bit_cast(h2,
                __builtin_amdgcn_cvt_pkrtz(ov[ds][4 * j + 2] * inv, ov[ds][4 * j + 3] * inv));
            *(h2*)&crow[d0]     = w0;
            *(h2*)&crow[d0 + 2] = w1;
        }
    }
}

// ---------------------------------------------------------------------------
// Kernel 3: output projection. out = comb @ Wo^T + bo, fp32 output.
// XCD-swizzled 1D grid (1024 = 8*128); K-step 64.
// ---------------------------------------------------------------------------
__global__ __launch_bounds__(256) void out_proj_kernel(
    const _Float16* __restrict__ comb, const float* __restrict__ Wo,
    const float* __restrict__ bo, float* __restrict__ out)
{
    const int bid = blockIdx.x;
    const int op  = (bid & 7) * 128 + (bid >> 3);
    const int ntile = op & 7;
    const int mt    = op >> 3;

    __shared__ _Float16 At[64][72];
    __shared__ _Float16 Bt[64][72];

    const int t = threadIdx.x;
    const int w = t >> 6;
    const int l = t & 63;
    const int mbase = mt * 64;
    const int nbase = ntile * 64;
    const int wm = (w >> 1) * 32;
    const int wn = (w & 1) * 32;
    const int fr = l & 15;
    const int gk = (l >> 4) * 8;
    const int srow = t >> 2;
    const int skol = (t & 3) * 16;

    f4 acc[2][2] = {};

    for (int kk = 0; kk < DM; kk += 64) {
        __syncthreads();
        {
            const _Float16* ap = comb + (size_t)(mbase + srow) * DM + kk + skol;
            *(h8*)&At[srow][skol]     = *(const h8*)ap;
            *(h8*)&At[srow][skol + 8] = *(const h8*)(ap + 8);

            const float* bp = Wo + (size_t)(nbase + srow) * DM + kk + skol;
            float4 b0 = *(const float4*)bp;
            float4 b1 = *(const float4*)(bp + 4);
            float4 b2 = *(const float4*)(bp + 8);
            float4 b3 = *(const float4*)(bp + 12);
            h8 bw0, bw1;
            bw0[0] = (_Float16)b0.x; bw0[1] = (_Float16)b0.y;
            bw0[2] = (_Float16)b0.z; bw0[3] = (_Float16)b0.w;
            bw0[4] = (_Float16)b1.x; bw0[5] = (_Float16)b1.y;
            bw0[6] = (_Float16)b1.z; bw0[7] = (_Float16)b1.w;
            bw1[0] = (_Float16)b2.x; bw1[1] = (_Float16)b2.y;
            bw1[2] = (_Float16)b2.z; bw1[3] = (_Float16)b2.w;
            bw1[4] = (_Float16)b3.x; bw1[5] = (_Float16)b3.y;
            bw1[6] = (_Float16)b3.z; bw1[7] = (_Float16)b3.w;
            *(h8*)&Bt[srow][skol]     = bw0;
            *(h8*)&Bt[srow][skol + 8] = bw1;
        }
        __syncthreads();

#pragma unroll
        for (int k2 = 0; k2 < 2; ++k2) {
            h8 af[2], bf[2];
#pragma unroll
            for (int mi = 0; mi < 2; ++mi)
                af[mi] = *(const h8*)&At[wm + mi * 16 + fr][k2 * 32 + gk];
#pragma unroll
            for (int ni = 0; ni < 2; ++ni)
                bf[ni] = *(const h8*)&Bt[wn + ni * 16 + fr][k2 * 32 + gk];
#pragma unroll
            for (int mi = 0; mi < 2; ++mi)
#pragma unroll
                for (int ni = 0; ni < 2; ++ni)
                    acc[mi][ni] = MFMA16(af[mi], bf[ni], acc[mi][ni]);
        }
    }

#pragma unroll
    for (int ni = 0; ni < 2; ++ni) {
        const int n = nbase + wn + ni * 16 + fr;
        const float bb = bo[n];
#pragma unroll
        for (int mi = 0; mi < 2; ++mi) {
#pragma unroll
            for (int r = 0; r < 4; ++r) {
                const int m = mbase + wm + mi * 16 + (l >> 4) * 4 + r;
                out[(size_t)m * DM + n] = acc[mi][ni][r] + bb;
            }
        }
    }
}

// ---------------------------------------------------------------------------
extern "C" void kernel_launch(void* const* d_in, const int* in_sizes, int n_in,
                              void* d_out, int out_size, void* d_ws, size_t ws_size,
                              hipStream_t stream)
{
    const float* Q    = (const float*)d_in[0];
    const float* K    = (const float*)d_in[1];
    const float* V    = (const float*)d_in[2];
    const int*   mask = (const int*)d_in[3];
    const float* Wq   = (const float*)d_in[4];
    const float* bq   = (const float*)d_in[5];
    const float* Wk   = (const float*)d_in[6];
    const float* bk   = (const float*)d_in[7];
    const float* Wv   = (const float*)d_in[8];
    const float* bv   = (const float*)d_in[9];
    const float* Wo   = (const float*)d_in[10];
    const float* bo   = (const float*)d_in[11];
    float* out = (float*)d_out;

    _Float16* ws = (_Float16*)d_ws;
    const size_t per = (size_t)NB * NH * SL * DK;
    _Float16* q_ws  = ws;
    _Float16* k_ws  = ws + per;
    _Float16* vT_ws = ws + 2 * per;
    _Float16* comb  = ws + 3 * per;

    proj_qkv_kernel<<<dim3(3072), 256, 0, stream>>>(
        Q, K, V, Wq, Wk, Wv, bq, bk, bv, q_ws, k_ws, vT_ws);

    attn_kernel<<<dim3(NB * NH, SL / QBLK), 256, 0, stream>>>(
        q_ws, k_ws, vT_ws, mask, comb);

    out_proj_kernel<<<dim3(1024), 256, 0, stream>>>(comb, Wo, bo, out);
}

// Round 6
// 144.542 us; speedup vs baseline: 1.1649x; 1.1649x over previous
//
#include <hip/hip_runtime.h>
#include <hip/hip_bf16.h>

typedef _Float16 h8 __attribute__((ext_vector_type(8)));
typedef _Float16 h4 __attribute__((ext_vector_type(4)));
typedef _Float16 h2 __attribute__((ext_vector_type(2)));
typedef float f2 __attribute__((ext_vector_type(2)));
typedef float f4 __attribute__((ext_vector_type(4)));
typedef float f16v __attribute__((ext_vector_type(16)));

#define MFMA32(a, b, c) __builtin_amdgcn_mfma_f32_32x32x16_f16(a, b, c, 0, 0, 0)

static constexpr int DM = 512;
static constexpr int SL = 4096;
static constexpr int NH = 8;
static constexpr int DK = 64;
static constexpr int NB = 2;

__device__ __forceinline__ h2 pk2(float a, float b) {
    return __builtin_bit_cast(h2, __builtin_amdgcn_cvt_pkrtz(a, b));
}
__device__ __forceinline__ h8 cvt8(float4 x, float4 y) {
    union { h2 h[4]; h8 v; } u;
    u.h[0] = pk2(x.x, x.y); u.h[1] = pk2(x.z, x.w);
    u.h[2] = pk2(y.x, y.y); u.h[3] = pk2(y.z, y.w);
    return u.v;
}

// ---------------------------------------------------------------------------
// Kernel 1: fused Q/K/V projections. 128x128 tile, BK=32, MFMA 32x32x16.
// A (X) and B (W) reg-staged fp32->fp16 (issue-early/write-late), XOR-swizzled
// LDS. q,k stored [B,H,S,64]; v transposed to [B,H,64,S] via LDS tile so
// global stores are coalesced. Grid 768 = 8 XCD x 96, panel-grouped.
// ---------------------------------------------------------------------------
__global__ __launch_bounds__(256) void proj_qkv_kernel(
    const float* __restrict__ Qin, const float* __restrict__ Kin,
    const float* __restrict__ Vin,
    const float* __restrict__ Wq, const float* __restrict__ Wk,
    const float* __restrict__ Wv,
    const float* __restrict__ bq, const float* __restrict__ bk,
    const float* __restrict__ bv,
    _Float16* __restrict__ qo, _Float16* __restrict__ ko,
    _Float16* __restrict__ vTo)
{
    const int bid = blockIdx.x;
    const int op  = (bid & 7) * 96 + (bid >> 3);
    const int nt    = op & 3;
    const int panel = op >> 2;          // 0..191
    const int which = panel >> 6;
    const int mt    = panel & 63;

    const float* __restrict__ X    = which == 0 ? Qin : (which == 1 ? Kin : Vin);
    const float* __restrict__ W    = which == 0 ? Wq  : (which == 1 ? Wk  : Wv);
    const float* __restrict__ bias = which == 0 ? bq  : (which == 1 ? bk  : bv);

    __shared__ __align__(16) _Float16 As[2][4096];   // [128][32], swizzled
    __shared__ __align__(16) _Float16 Bs[2][4096];
    __shared__ __align__(16) _Float16 Vtr[64][144];  // transpose staging

    const int t   = threadIdx.x;
    const int w   = t >> 6;
    const int l   = t & 63;
    const int l31 = l & 31;
    const int hi  = l >> 5;
    const int mbase = mt * 128;
    const int nbase = nt * 128;
    const int wm = (w >> 1) * 64;
    const int wn = (w & 1) * 64;

    // staging ids (2 chunks per thread per tile)
    const int id0 = t, id1 = 256 + t;
    const int r0 = id0 >> 2, c0 = id0 & 3;
    const int r1 = id1 >> 2, c1 = id1 & 3;
    const int sl0 = (c0 ^ (r0 & 3)) * 8;
    const int sl1 = (c1 ^ (r1 & 3)) * 8;
    const float* Xp0 = X + (size_t)(mbase + r0) * DM + c0 * 8;
    const float* Xp1 = X + (size_t)(mbase + r1) * DM + c1 * 8;
    const float* Wp0 = W + (size_t)(nbase + r0) * DM + c0 * 8;
    const float* Wp1 = W + (size_t)(nbase + r1) * DM + c1 * 8;

    f16v acc[2][2] = {};

    // prologue: stage step 0
    {
        float4 a00 = *(const float4*)(Xp0), a01 = *(const float4*)(Xp0 + 4);
        float4 a10 = *(const float4*)(Xp1), a11 = *(const float4*)(Xp1 + 4);
        float4 b00 = *(const float4*)(Wp0), b01 = *(const float4*)(Wp0 + 4);
        float4 b10 = *(const float4*)(Wp1), b11 = *(const float4*)(Wp1 + 4);
        *(h8*)&As[0][r0 * 32 + sl0] = cvt8(a00, a01);
        *(h8*)&As[0][r1 * 32 + sl1] = cvt8(a10, a11);
        *(h8*)&Bs[0][r0 * 32 + sl0] = cvt8(b00, b01);
        *(h8*)&Bs[0][r1 * 32 + sl1] = cvt8(b10, b11);
    }
    __syncthreads();

    int cur = 0;
    for (int step = 0; step < 16; ++step) {
        const int kn = (step + 1) * 32;
        float4 a00, a01, a10, a11, b00, b01, b10, b11;
        const bool more = step + 1 < 16;
        if (more) {
            a00 = *(const float4*)(Xp0 + kn); a01 = *(const float4*)(Xp0 + kn + 4);
            a10 = *(const float4*)(Xp1 + kn); a11 = *(const float4*)(Xp1 + kn + 4);
            b00 = *(const float4*)(Wp0 + kn); b01 = *(const float4*)(Wp0 + kn + 4);
            b10 = *(const float4*)(Wp1 + kn); b11 = *(const float4*)(Wp1 + kn + 4);
        }

        const _Float16* Ac = As[cur];
        const _Float16* Bc = Bs[cur];
        h8 af[2][2], bf[2][2];
#pragma unroll
        for (int ti = 0; ti < 2; ++ti)
#pragma unroll
            for (int s = 0; s < 2; ++s)
                af[ti][s] = *(const h8*)&Ac[(wm + ti * 32 + l31) * 32 +
                                            (((2 * s + hi) ^ (l31 & 3)) << 3)];
#pragma unroll
        for (int tj = 0; tj < 2; ++tj)
#pragma unroll
            for (int s = 0; s < 2; ++s)
                bf[tj][s] = *(const h8*)&Bc[(wn + tj * 32 + l31) * 32 +
                                            (((2 * s + hi) ^ (l31 & 3)) << 3)];
        __builtin_amdgcn_s_setprio(1);
#pragma unroll
        for (int ti = 0; ti < 2; ++ti)
#pragma unroll
            for (int tj = 0; tj < 2; ++tj)
#pragma unroll
                for (int s = 0; s < 2; ++s)
                    acc[ti][tj] = MFMA32(af[ti][s], bf[tj][s], acc[ti][tj]);
        __builtin_amdgcn_s_setprio(0);

        if (more) {
            const int nb2 = cur ^ 1;
            *(h8*)&As[nb2][r0 * 32 + sl0] = cvt8(a00, a01);
            *(h8*)&As[nb2][r1 * 32 + sl1] = cvt8(a10, a11);
            *(h8*)&Bs[nb2][r0 * 32 + sl0] = cvt8(b00, b01);
            *(h8*)&Bs[nb2][r1 * 32 + sl1] = cvt8(b10, b11);
        }
        __syncthreads();
        cur ^= 1;
    }

    if (which < 2) {
        _Float16* dst = (which == 0) ? qo : ko;
#pragma unroll
        for (int tj = 0; tj < 2; ++tj) {
            const int n  = nbase + wn + tj * 32 + l31;
            const float bb = bias[n];
            const int hh = n >> 6;
            const int d  = n & 63;
#pragma unroll
            for (int ti = 0; ti < 2; ++ti) {
#pragma unroll
                for (int j = 0; j < 4; ++j) {
#pragma unroll
                    for (int c = 0; c < 4; ++c) {
                        const int m = mbase + wm + ti * 32 + 8 * j + 4 * hi + c;
                        const int bi = m >> 12;
                        const int s  = m & 4095;
                        dst[((size_t)(bi * NH + hh) * SL + s) * DK + d] =
                            (_Float16)(acc[ti][tj][4 * j + c] + bb);
                    }
                }
            }
        }
    } else {
        const int bi = mbase >> 12;
        const int s0 = mbase & 4095;
#pragma unroll
        for (int nh = 0; nh < 2; ++nh) {
            __syncthreads();
            if ((w & 1) == nh) {
#pragma unroll
                for (int tj = 0; tj < 2; ++tj) {
                    const int d = tj * 32 + l31;
                    const float bb = bias[nbase + nh * 64 + d];
#pragma unroll
                    for (int ti = 0; ti < 2; ++ti) {
#pragma unroll
                        for (int j = 0; j < 4; ++j) {
                            h2 x0 = pk2(acc[ti][tj][4 * j] + bb,
                                        acc[ti][tj][4 * j + 1] + bb);
                            h2 x1 = pk2(acc[ti][tj][4 * j + 2] + bb,
                                        acc[ti][tj][4 * j + 3] + bb);
                            h4 val = {x0[0], x0[1], x1[0], x1[1]};
                            *(h4*)&Vtr[d][wm + ti * 32 + 8 * j + 4 * hi] = val;
                        }
                    }
                }
            }
            __syncthreads();
            {
                const int d = t >> 2, part = t & 3;
                const int hh = nt * 2 + nh;
                _Float16* dstv = vTo + ((size_t)(bi * NH + hh) * DK + d) * SL +
                                 s0 + part * 32;
                h8 v0 = *(const h8*)&Vtr[d][part * 32];
                h8 v1 = *(const h8*)&Vtr[d][part * 32 + 8];
                h8 v2 = *(const h8*)&Vtr[d][part * 32 + 16];
                h8 v3 = *(const h8*)&Vtr[d][part * 32 + 24];
                *(h8*)(dstv)      = v0;
                *(h8*)(dstv + 8)  = v1;
                *(h8*)(dstv + 16) = v2;
                *(h8*)(dstv + 24) = v3;
            }
        }
    }
}

// ---------------------------------------------------------------------------
// Kernel 2: flash attention. KVBLK=128 double-buffered staging (32 barriers),
// swapped QK^T + in-register P, mask bias as MFMA C-init, row-sum via
// all-ones MFMA (no per-lane adds, no final shuffle).
// ---------------------------------------------------------------------------
static constexpr int KVB  = 128;
static constexpr int NT2  = SL / KVB;   // 32
static constexpr int QBLK = 128;

__device__ __forceinline__ void stage_tiles(
    _Float16* Ktb, _Float16* Vtb,
    const _Float16* kbh, const _Float16* vbh, int kb, int t)
{
    const int w = t >> 6, l = t & 63;
    const char* ksrc = (const char*)(kbh + (size_t)kb * DK);  // 16KB contiguous
#pragma unroll
    for (int s2 = 0; s2 < 4; ++s2) {
        const int c  = s2 * 256 + w * 64 + l;     // 0..1023
        const int kr = c >> 3;                    // staged key row 0..127
        const int sl = c & 7;
        const int srow = (kr & ~12) | ((kr & 4) << 1) | ((kr & 8) >> 1);
        const int cs = srow * 8 + (sl ^ (kr & 7));
        char* dst = (char*)Ktb + (size_t)(s2 * 256 + w * 64) * 16;
        __builtin_amdgcn_global_load_lds(
            (const __attribute__((address_space(1))) void*)(ksrc + (size_t)cs * 16),
            (__attribute__((address_space(3))) void*)dst, 16, 0, 0);
    }
#pragma unroll
    for (int s2 = 0; s2 < 4; ++s2) {
        const int c   = s2 * 256 + w * 64 + l;
        const int sub = c >> 9;                   // 64-key half
        const int c2  = c & 511;
        const int d   = c2 >> 3;
        const int sl  = c2 & 7;
        const _Float16* src = vbh + (size_t)d * SL + kb + sub * 64 +
                              (sl ^ (d & 7)) * 8;
        char* dst = (char*)Vtb + (size_t)(s2 * 256 + w * 64) * 16;
        __builtin_amdgcn_global_load_lds(
            (const __attribute__((address_space(1))) void*)src,
            (__attribute__((address_space(3))) void*)dst, 16, 0, 0);
    }
}

__global__ __launch_bounds__(256) void attn_kernel(
    const _Float16* __restrict__ qg, const _Float16* __restrict__ kg,
    const _Float16* __restrict__ vTg, const int* __restrict__ mask,
    _Float16* __restrict__ comb)
{
    const int t   = threadIdx.x;
    const int w   = t >> 6;
    const int l   = t & 63;
    const int l31 = l & 31;
    const int hi  = l >> 5;
    const int r7  = l31 & 7;
    const int hh  = blockIdx.x & 7;
    const int b   = blockIdx.x >> 3;
    const int qt  = blockIdx.y;

    const _Float16* qbh = qg  + (size_t)(b * NH + hh) * SL * DK;
    const _Float16* kbh = kg  + (size_t)(b * NH + hh) * SL * DK;
    const _Float16* vbh = vTg + (size_t)(b * NH + hh) * DK * SL;
    const int* mrow = mask + b * SL;

    __shared__ __align__(16) _Float16 Kt[2][8192];  // 2 x [2 half][64][64]
    __shared__ __align__(16) _Float16 Vt[2][8192];
    __shared__ __align__(16) float bias_tab[SL];

#pragma unroll
    for (int j = 0; j < 4; ++j) {
        int4 v = *(const int4*)&mrow[t * 16 + j * 4];
        f4 bv;
        bv[0] = v.x ? 0.f : -1e38f; bv[1] = v.y ? 0.f : -1e38f;
        bv[2] = v.z ? 0.f : -1e38f; bv[3] = v.w ? 0.f : -1e38f;
        *(f4*)&bias_tab[t * 16 + j * 4] = bv;
    }

    const _Float16 sch = (_Float16)(0.125f * 1.44269504089f);
    const h8 sc8 = {sch, sch, sch, sch, sch, sch, sch, sch};
    h8 qf[4];
    {
        const _Float16* qp = qbh + (size_t)(qt * QBLK + w * 32 + l31) * DK + hi * 8;
#pragma unroll
        for (int st = 0; st < 4; ++st)
            qf[st] = *(const h8*)(qp + st * 16) * sc8;
    }

    const _Float16 oneh = (_Float16)1.0f;
    const h8 ones = {oneh, oneh, oneh, oneh, oneh, oneh, oneh, oneh};

    stage_tiles(Kt[0], Vt[0], kbh, vbh, 0, t);
    __syncthreads();

    f16v ov[2] = {};
    f16v osum  = {};

    int cur = 0;
    for (int kt = 0; kt < NT2; ++kt) {
        const int kb = kt * KVB;
        if (kt + 1 < NT2)
            stage_tiles(Kt[cur ^ 1], Vt[cur ^ 1], kbh, vbh, kb + KVB, t);

#pragma unroll
        for (int kh = 0; kh < 2; ++kh) {
            const _Float16* Kc = Kt[cur] + kh * 4096;
            const _Float16* Vc = Vt[cur] + kh * 4096;
            const int kbb = kb + kh * 64;

            f16v sc[2];
#pragma unroll
            for (int s = 0; s < 2; ++s) {
                union { f2 q[8]; f16v v; } u;
#pragma unroll
                for (int j = 0; j < 4; ++j) {
                    const int base = kbb + s * 32 + ((j >> 1) << 4) +
                                     ((j & 1) << 2) + (hi << 3);
                    u.q[2 * j]     = *(const f2*)&bias_tab[base];
                    u.q[2 * j + 1] = *(const f2*)&bias_tab[base + 2];
                }
                sc[s] = u.v;
            }

            __builtin_amdgcn_s_setprio(1);
#pragma unroll
            for (int s = 0; s < 2; ++s) {
                const int rb = (s * 32 + l31) * 64;
#pragma unroll
                for (int st = 0; st < 4; ++st) {
                    h8 a = *(const h8*)&Kc[rb + (((st * 2 + hi) ^ r7) << 3)];
                    sc[s] = MFMA32(a, qf[st], sc[s]);
                }
            }
            __builtin_amdgcn_s_setprio(0);

#pragma unroll
            for (int s = 0; s < 2; ++s)
#pragma unroll
                for (int r = 0; r < 16; ++r)
                    sc[s][r] = __builtin_amdgcn_exp2f(sc[s][r]);

            __builtin_amdgcn_s_setprio(1);
#pragma unroll
            for (int ks = 0; ks < 4; ++ks) {
                const int s  = ks >> 1;
                const int e0 = (ks & 1) * 8;
                union { h2 h[4]; h8 v; } pf;
#pragma unroll
                for (int u2 = 0; u2 < 4; ++u2)
                    pf.h[u2] = pk2(sc[s][e0 + 2 * u2], sc[s][e0 + 2 * u2 + 1]);
#pragma unroll
                for (int ds = 0; ds < 2; ++ds) {
                    h8 av = *(const h8*)&Vc[(ds * 32 + l31) * 64 +
                                            (((ks * 2 + hi) ^ r7) << 3)];
                    ov[ds] = MFMA32(av, pf.v, ov[ds]);
                }
                osum = MFMA32(ones, pf.v, osum);
            }
            __builtin_amdgcn_s_setprio(0);
        }

        __syncthreads();
        cur ^= 1;
    }

    const float inv = 1.0f / osum[0];

    _Float16* crow = comb + (size_t)(b * SL + qt * QBLK + w * 32 + l31) * DM + hh * DK;
#pragma unroll
    for (int ds = 0; ds < 2; ++ds) {
#pragma unroll
        for (int j = 0; j < 4; ++j) {
            const int d0 = ds * 32 + j * 8 + hi * 4;
            h2 w0 = pk2(ov[ds][4 * j] * inv,     ov[ds][4 * j + 1] * inv);
            h2 w1 = pk2(ov[ds][4 * j + 2] * inv, ov[ds][4 * j + 3] * inv);
            *(h2*)&crow[d0]     = w0;
            *(h2*)&crow[d0 + 2] = w1;
        }
    }
}

// ---------------------------------------------------------------------------
// Kernel 3: output projection. 128x128 tile, BK=32. A (comb, fp16) staged via
// global_load_lds with source-swizzle; B (Wo, fp32) reg-staged. fp32 out.
// ---------------------------------------------------------------------------
__global__ __launch_bounds__(256) void out_proj_kernel(
    const _Float16* __restrict__ comb, const float* __restrict__ Wo,
    const float* __restrict__ bo, float* __restrict__ out)
{
    const int bid = blockIdx.x;
    const int op  = (bid & 7) * 32 + (bid >> 3);
    const int nt  = op & 3;
    const int mt  = op >> 2;

    __shared__ __align__(16) _Float16 As[2][4096];
    __shared__ __align__(16) _Float16 Bs[2][4096];

    const int t   = threadIdx.x;
    const int w   = t >> 6;
    const int l   = t & 63;
    const int l31 = l & 31;
    const int hi  = l >> 5;
    const int mbase = mt * 128;
    const int nbase = nt * 128;
    const int wm = (w >> 1) * 64;
    const int wn = (w & 1) * 64;

    const int id0 = t, id1 = 256 + t;
    const int r0 = id0 >> 2, c0 = id0 & 3;
    const int r1 = id1 >> 2, c1 = id1 & 3;
    const int sl0 = (c0 ^ (r0 & 3)) * 8;
    const int sl1 = (c1 ^ (r1 & 3)) * 8;
    // A source (swizzled chunk within row)
    const _Float16* Ap0 = comb + (size_t)(mbase + r0) * DM + (c0 ^ (r0 & 3)) * 8;
    const _Float16* Ap1 = comb + (size_t)(mbase + r1) * DM + (c1 ^ (r1 & 3)) * 8;
    const float* Wp0 = Wo + (size_t)(nbase + r0) * DM + c0 * 8;
    const float* Wp1 = Wo + (size_t)(nbase + r1) * DM + c1 * 8;

    auto stageA = [&](int buf, int kk) {
        char* d0 = (char*)&As[buf][0] + (size_t)id0 * 16;
        char* d1 = (char*)&As[buf][0] + (size_t)id1 * 16;
        __builtin_amdgcn_global_load_lds(
            (const __attribute__((address_space(1))) void*)(Ap0 + kk),
            (__attribute__((address_space(3))) void*)d0, 16, 0, 0);
        __builtin_amdgcn_global_load_lds(
            (const __attribute__((address_space(1))) void*)(Ap1 + kk),
            (__attribute__((address_space(3))) void*)d1, 16, 0, 0);
    };

    f16v acc[2][2] = {};

    stageA(0, 0);
    {
        float4 b00 = *(const float4*)(Wp0), b01 = *(const float4*)(Wp0 + 4);
        float4 b10 = *(const float4*)(Wp1), b11 = *(const float4*)(Wp1 + 4);
        *(h8*)&Bs[0][r0 * 32 + sl0] = cvt8(b00, b01);
        *(h8*)&Bs[0][r1 * 32 + sl1] = cvt8(b10, b11);
    }
    __syncthreads();

    int cur = 0;
    for (int step = 0; step < 16; ++step) {
        const int kn = (step + 1) * 32;
        const bool more = step + 1 < 16;
        float4 b00, b01, b10, b11;
        if (more) {
            stageA(cur ^ 1, kn);
            b00 = *(const float4*)(Wp0 + kn); b01 = *(const float4*)(Wp0 + kn + 4);
            b10 = *(const float4*)(Wp1 + kn); b11 = *(const float4*)(Wp1 + kn + 4);
        }

        const _Float16* Ac = As[cur];
        const _Float16* Bc = Bs[cur];
        h8 af[2][2], bf[2][2];
#pragma unroll
        for (int ti = 0; ti < 2; ++ti)
#pragma unroll
            for (int s = 0; s < 2; ++s)
                af[ti][s] = *(const h8*)&Ac[(wm + ti * 32 + l31) * 32 +
                                            (((2 * s + hi) ^ (l31 & 3)) << 3)];
#pragma unroll
        for (int tj = 0; tj < 2; ++tj)
#pragma unroll
            for (int s = 0; s < 2; ++s)
                bf[tj][s] = *(const h8*)&Bc[(wn + tj * 32 + l31) * 32 +
                                            (((2 * s + hi) ^ (l31 & 3)) << 3)];
        __builtin_amdgcn_s_setprio(1);
#pragma unroll
        for (int ti = 0; ti < 2; ++ti)
#pragma unroll
            for (int tj = 0; tj < 2; ++tj)
#pragma unroll
                for (int s = 0; s < 2; ++s)
                    acc[ti][tj] = MFMA32(af[ti][s], bf[tj][s], acc[ti][tj]);
        __builtin_amdgcn_s_setprio(0);

        if (more) {
            const int nb2 = cur ^ 1;
            *(h8*)&Bs[nb2][r0 * 32 + sl0] = cvt8(b00, b01);
            *(h8*)&Bs[nb2][r1 * 32 + sl1] = cvt8(b10, b11);
        }
        __syncthreads();
        cur ^= 1;
    }

#pragma unroll
    for (int tj = 0; tj < 2; ++tj) {
        const int n = nbase + wn + tj * 32 + l31;
        const float bb = bo[n];
#pragma unroll
        for (int ti = 0; ti < 2; ++ti) {
#pragma unroll
            for (int j = 0; j < 4; ++j) {
#pragma unroll
                for (int c = 0; c < 4; ++c) {
                    const int m = mbase + wm + ti * 32 + 8 * j + 4 * hi + c;
                    out[(size_t)m * DM + n] = acc[ti][tj][4 * j + c] + bb;
                }
            }
        }
    }
}

// ---------------------------------------------------------------------------
extern "C" void kernel_launch(void* const* d_in, const int* in_sizes, int n_in,
                              void* d_out, int out_size, void* d_ws, size_t ws_size,
                              hipStream_t stream)
{
    const float* Q    = (const float*)d_in[0];
    const float* K    = (const float*)d_in[1];
    const float* V    = (const float*)d_in[2];
    const int*   mask = (const int*)d_in[3];
    const float* Wq   = (const float*)d_in[4];
    const float* bq   = (const float*)d_in[5];
    const float* Wk   = (const float*)d_in[6];
    const float* bk   = (const float*)d_in[7];
    const float* Wv   = (const float*)d_in[8];
    const float* bv   = (const float*)d_in[9];
    const float* Wo   = (const float*)d_in[10];
    const float* bo   = (const float*)d_in[11];
    float* out = (float*)d_out;

    _Float16* ws = (_Float16*)d_ws;
    const size_t per = (size_t)NB * NH * SL * DK;
    _Float16* q_ws  = ws;
    _Float16* k_ws  = ws + per;
    _Float16* vT_ws = ws + 2 * per;
    _Float16* comb  = ws + 3 * per;

    proj_qkv_kernel<<<dim3(768), 256, 0, stream>>>(
        Q, K, V, Wq, Wk, Wv, bq, bk, bv, q_ws, k_ws, vT_ws);

    attn_kernel<<<dim3(NB * NH, SL / QBLK), 256, 0, stream>>>(
        q_ws, k_ws, vT_ws, mask, comb);

    out_proj_kernel<<<dim3(256), 256, 0, stream>>>(comb, Wo, bo, out);
}

// Round 7
// 142.559 us; speedup vs baseline: 1.1811x; 1.0139x over previous
//
#include <hip/hip_runtime.h>
#include <hip/hip_bf16.h>

typedef _Float16 h8 __attribute__((ext_vector_type(8)));
typedef _Float16 h4 __attribute__((ext_vector_type(4)));
typedef _Float16 h2 __attribute__((ext_vector_type(2)));
typedef float f2 __attribute__((ext_vector_type(2)));
typedef float f4 __attribute__((ext_vector_type(4)));
typedef float f16v __attribute__((ext_vector_type(16)));

#define MFMA32(a, b, c) __builtin_amdgcn_mfma_f32_32x32x16_f16(a, b, c, 0, 0, 0)

static constexpr int DM = 512;
static constexpr int SL = 4096;
static constexpr int NH = 8;
static constexpr int DK = 64;
static constexpr int NB = 2;

__device__ __forceinline__ h2 pk2(float a, float b) {
    return __builtin_bit_cast(h2, __builtin_amdgcn_cvt_pkrtz(a, b));
}
__device__ __forceinline__ h8 cvt8(float4 x, float4 y) {
    union { h2 h[4]; h8 v; } u;
    u.h[0] = pk2(x.x, x.y); u.h[1] = pk2(x.z, x.w);
    u.h[2] = pk2(y.x, y.y); u.h[3] = pk2(y.z, y.w);
    return u.v;
}

// ---------------------------------------------------------------------------
// Kernel 1: fused Q/K/V projections. 128x128 tile, BK=32, MFMA 32x32x16.
// (unchanged from round 6)
// ---------------------------------------------------------------------------
__global__ __launch_bounds__(256) void proj_qkv_kernel(
    const float* __restrict__ Qin, const float* __restrict__ Kin,
    const float* __restrict__ Vin,
    const float* __restrict__ Wq, const float* __restrict__ Wk,
    const float* __restrict__ Wv,
    const float* __restrict__ bq, const float* __restrict__ bk,
    const float* __restrict__ bv,
    _Float16* __restrict__ qo, _Float16* __restrict__ ko,
    _Float16* __restrict__ vTo)
{
    const int bid = blockIdx.x;
    const int op  = (bid & 7) * 96 + (bid >> 3);
    const int nt    = op & 3;
    const int panel = op >> 2;
    const int which = panel >> 6;
    const int mt    = panel & 63;

    const float* __restrict__ X    = which == 0 ? Qin : (which == 1 ? Kin : Vin);
    const float* __restrict__ W    = which == 0 ? Wq  : (which == 1 ? Wk  : Wv);
    const float* __restrict__ bias = which == 0 ? bq  : (which == 1 ? bk  : bv);

    __shared__ __align__(16) _Float16 As[2][4096];
    __shared__ __align__(16) _Float16 Bs[2][4096];
    __shared__ __align__(16) _Float16 Vtr[64][144];

    const int t   = threadIdx.x;
    const int w   = t >> 6;
    const int l   = t & 63;
    const int l31 = l & 31;
    const int hi  = l >> 5;
    const int mbase = mt * 128;
    const int nbase = nt * 128;
    const int wm = (w >> 1) * 64;
    const int wn = (w & 1) * 64;

    const int id0 = t, id1 = 256 + t;
    const int r0 = id0 >> 2, c0 = id0 & 3;
    const int r1 = id1 >> 2, c1 = id1 & 3;
    const int sl0 = (c0 ^ (r0 & 3)) * 8;
    const int sl1 = (c1 ^ (r1 & 3)) * 8;
    const float* Xp0 = X + (size_t)(mbase + r0) * DM + c0 * 8;
    const float* Xp1 = X + (size_t)(mbase + r1) * DM + c1 * 8;
    const float* Wp0 = W + (size_t)(nbase + r0) * DM + c0 * 8;
    const float* Wp1 = W + (size_t)(nbase + r1) * DM + c1 * 8;

    f16v acc[2][2] = {};

    {
        float4 a00 = *(const float4*)(Xp0), a01 = *(const float4*)(Xp0 + 4);
        float4 a10 = *(const float4*)(Xp1), a11 = *(const float4*)(Xp1 + 4);
        float4 b00 = *(const float4*)(Wp0), b01 = *(const float4*)(Wp0 + 4);
        float4 b10 = *(const float4*)(Wp1), b11 = *(const float4*)(Wp1 + 4);
        *(h8*)&As[0][r0 * 32 + sl0] = cvt8(a00, a01);
        *(h8*)&As[0][r1 * 32 + sl1] = cvt8(a10, a11);
        *(h8*)&Bs[0][r0 * 32 + sl0] = cvt8(b00, b01);
        *(h8*)&Bs[0][r1 * 32 + sl1] = cvt8(b10, b11);
    }
    __syncthreads();

    int cur = 0;
    for (int step = 0; step < 16; ++step) {
        const int kn = (step + 1) * 32;
        float4 a00, a01, a10, a11, b00, b01, b10, b11;
        const bool more = step + 1 < 16;
        if (more) {
            a00 = *(const float4*)(Xp0 + kn); a01 = *(const float4*)(Xp0 + kn + 4);
            a10 = *(const float4*)(Xp1 + kn); a11 = *(const float4*)(Xp1 + kn + 4);
            b00 = *(const float4*)(Wp0 + kn); b01 = *(const float4*)(Wp0 + kn + 4);
            b10 = *(const float4*)(Wp1 + kn); b11 = *(const float4*)(Wp1 + kn + 4);
        }

        const _Float16* Ac = As[cur];
        const _Float16* Bc = Bs[cur];
        h8 af[2][2], bf[2][2];
#pragma unroll
        for (int ti = 0; ti < 2; ++ti)
#pragma unroll
            for (int s = 0; s < 2; ++s)
                af[ti][s] = *(const h8*)&Ac[(wm + ti * 32 + l31) * 32 +
                                            (((2 * s + hi) ^ (l31 & 3)) << 3)];
#pragma unroll
        for (int tj = 0; tj < 2; ++tj)
#pragma unroll
            for (int s = 0; s < 2; ++s)
                bf[tj][s] = *(const h8*)&Bc[(wn + tj * 32 + l31) * 32 +
                                            (((2 * s + hi) ^ (l31 & 3)) << 3)];
        __builtin_amdgcn_s_setprio(1);
#pragma unroll
        for (int ti = 0; ti < 2; ++ti)
#pragma unroll
            for (int tj = 0; tj < 2; ++tj)
#pragma unroll
                for (int s = 0; s < 2; ++s)
                    acc[ti][tj] = MFMA32(af[ti][s], bf[tj][s], acc[ti][tj]);
        __builtin_amdgcn_s_setprio(0);

        if (more) {
            const int nb2 = cur ^ 1;
            *(h8*)&As[nb2][r0 * 32 + sl0] = cvt8(a00, a01);
            *(h8*)&As[nb2][r1 * 32 + sl1] = cvt8(a10, a11);
            *(h8*)&Bs[nb2][r0 * 32 + sl0] = cvt8(b00, b01);
            *(h8*)&Bs[nb2][r1 * 32 + sl1] = cvt8(b10, b11);
        }
        __syncthreads();
        cur ^= 1;
    }

    if (which < 2) {
        _Float16* dst = (which == 0) ? qo : ko;
#pragma unroll
        for (int tj = 0; tj < 2; ++tj) {
            const int n  = nbase + wn + tj * 32 + l31;
            const float bb = bias[n];
            const int hh = n >> 6;
            const int d  = n & 63;
#pragma unroll
            for (int ti = 0; ti < 2; ++ti) {
#pragma unroll
                for (int j = 0; j < 4; ++j) {
#pragma unroll
                    for (int c = 0; c < 4; ++c) {
                        const int m = mbase + wm + ti * 32 + 8 * j + 4 * hi + c;
                        const int bi = m >> 12;
                        const int s  = m & 4095;
                        dst[((size_t)(bi * NH + hh) * SL + s) * DK + d] =
                            (_Float16)(acc[ti][tj][4 * j + c] + bb);
                    }
                }
            }
        }
    } else {
        const int bi = mbase >> 12;
        const int s0 = mbase & 4095;
#pragma unroll
        for (int nh = 0; nh < 2; ++nh) {
            __syncthreads();
            if ((w & 1) == nh) {
#pragma unroll
                for (int tj = 0; tj < 2; ++tj) {
                    const int d = tj * 32 + l31;
                    const float bb = bias[nbase + nh * 64 + d];
#pragma unroll
                    for (int ti = 0; ti < 2; ++ti) {
#pragma unroll
                        for (int j = 0; j < 4; ++j) {
                            h2 x0 = pk2(acc[ti][tj][4 * j] + bb,
                                        acc[ti][tj][4 * j + 1] + bb);
                            h2 x1 = pk2(acc[ti][tj][4 * j + 2] + bb,
                                        acc[ti][tj][4 * j + 3] + bb);
                            h4 val = {x0[0], x0[1], x1[0], x1[1]};
                            *(h4*)&Vtr[d][wm + ti * 32 + 8 * j + 4 * hi] = val;
                        }
                    }
                }
            }
            __syncthreads();
            {
                const int d = t >> 2, part = t & 3;
                const int hh = nt * 2 + nh;
                _Float16* dstv = vTo + ((size_t)(bi * NH + hh) * DK + d) * SL +
                                 s0 + part * 32;
                h8 v0 = *(const h8*)&Vtr[d][part * 32];
                h8 v1 = *(const h8*)&Vtr[d][part * 32 + 8];
                h8 v2 = *(const h8*)&Vtr[d][part * 32 + 16];
                h8 v3 = *(const h8*)&Vtr[d][part * 32 + 24];
                *(h8*)(dstv)      = v0;
                *(h8*)(dstv + 8)  = v1;
                *(h8*)(dstv + 16) = v2;
                *(h8*)(dstv + 24) = v3;
            }
        }
    }
}

// ---------------------------------------------------------------------------
// Kernel 2: flash attention, K-split=2 (blockIdx.z = key half).
// Partial O (fp16, scaled 2^-12) + partial l (f32) written per split; no
// cross-split combine here. KVBLK=64, LDS 40KB -> 4 blocks/CU, 4 waves/SIMD.
// ---------------------------------------------------------------------------
static constexpr int QBLK  = 128;
static constexpr int KSPL  = 2;
static constexpr int KHALF = SL / KSPL;   // 2048
static constexpr int NTS   = KHALF / 64;  // 32

__device__ __forceinline__ void stage_tiles(
    _Float16* Ktb, _Float16* Vtb,
    const _Float16* kbh, const _Float16* vbh, int kb, int t)
{
    const int w = t >> 6, l = t & 63;
    const char* ksrc = (const char*)(kbh + (size_t)kb * DK);
#pragma unroll
    for (int s2 = 0; s2 < 2; ++s2) {
        const int c  = s2 * 256 + w * 64 + l;
        const int kr = c >> 3;
        const int sl = c & 7;
        const int srow = (kr & ~12) | ((kr & 4) << 1) | ((kr & 8) >> 1);
        const int cs = srow * 8 + (sl ^ (kr & 7));
        char* dst = (char*)Ktb + (size_t)(s2 * 4096 + w * 1024);
        __builtin_amdgcn_global_load_lds(
            (const __attribute__((address_space(1))) void*)(ksrc + (size_t)cs * 16),
            (__attribute__((address_space(3))) void*)dst, 16, 0, 0);
    }
#pragma unroll
    for (int s2 = 0; s2 < 2; ++s2) {
        const int c  = s2 * 256 + w * 64 + l;
        const int d  = c >> 3;
        const int cs = (c & 7) ^ (d & 7);
        const _Float16* src = vbh + (size_t)d * SL + kb + cs * 8;
        char* dst = (char*)Vtb + (size_t)(s2 * 4096 + w * 1024);
        __builtin_amdgcn_global_load_lds(
            (const __attribute__((address_space(1))) void*)src,
            (__attribute__((address_space(3))) void*)dst, 16, 0, 0);
    }
}

__global__ __launch_bounds__(256) void attn_kernel(
    const _Float16* __restrict__ qg, const _Float16* __restrict__ kg,
    const _Float16* __restrict__ vTg, const int* __restrict__ mask,
    _Float16* __restrict__ o_ws, float* __restrict__ l_ws)
{
    const int t   = threadIdx.x;
    const int w   = t >> 6;
    const int l   = t & 63;
    const int l31 = l & 31;
    const int hi  = l >> 5;
    const int r7  = l31 & 7;
    const int hh  = blockIdx.x & 7;
    const int b   = blockIdx.x >> 3;
    const int qt  = blockIdx.y;
    const int split = blockIdx.z;
    const int koff  = split * KHALF;

    const _Float16* qbh = qg  + (size_t)(b * NH + hh) * SL * DK;
    const _Float16* kbh = kg  + (size_t)(b * NH + hh) * SL * DK;
    const _Float16* vbh = vTg + (size_t)(b * NH + hh) * DK * SL;
    const int* mrow = mask + b * SL;

    __shared__ __align__(16) _Float16 Kt[2][4096];
    __shared__ __align__(16) _Float16 Vt[2][4096];
    __shared__ __align__(16) float bias_tab[KHALF];   // 8 KB

    // mask -> f32 bias table for this key half (8 entries/thread)
#pragma unroll
    for (int j = 0; j < 2; ++j) {
        int4 v = *(const int4*)&mrow[koff + t * 8 + j * 4];
        f4 bv;
        bv[0] = v.x ? 0.f : -1e38f; bv[1] = v.y ? 0.f : -1e38f;
        bv[2] = v.z ? 0.f : -1e38f; bv[3] = v.w ? 0.f : -1e38f;
        *(f4*)&bias_tab[t * 8 + j * 4] = bv;
    }

    const _Float16 sch = (_Float16)(0.125f * 1.44269504089f);
    const h8 sc8 = {sch, sch, sch, sch, sch, sch, sch, sch};
    h8 qf[4];
    {
        const _Float16* qp = qbh + (size_t)(qt * QBLK + w * 32 + l31) * DK + hi * 8;
#pragma unroll
        for (int st = 0; st < 4; ++st)
            qf[st] = *(const h8*)(qp + st * 16) * sc8;
    }

    stage_tiles(Kt[0], Vt[0], kbh, vbh, koff, t);
    __syncthreads();

    f16v ov[2] = {};
    float ls0 = 0.f, ls1 = 0.f;

    int cur = 0;
    for (int kt = 0; kt < NTS; ++kt) {
        const int kb = koff + kt * 64;
        if (kt + 1 < NTS)
            stage_tiles(Kt[cur ^ 1], Vt[cur ^ 1], kbh, vbh, kb + 64, t);

        const _Float16* Kc = Kt[cur];
        const _Float16* Vc = Vt[cur];
        const int lb = kt * 64;   // local bias base

        f16v sc[2];
#pragma unroll
        for (int s = 0; s < 2; ++s) {
            union { f2 q[8]; f16v v; } u;
#pragma unroll
            for (int j = 0; j < 4; ++j) {
                const int base = lb + s * 32 + ((j >> 1) << 4) +
                                 ((j & 1) << 2) + (hi << 3);
                u.q[2 * j]     = *(const f2*)&bias_tab[base];
                u.q[2 * j + 1] = *(const f2*)&bias_tab[base + 2];
            }
            sc[s] = u.v;
        }

        __builtin_amdgcn_s_setprio(1);
#pragma unroll
        for (int s = 0; s < 2; ++s) {
            const int rb = (s * 32 + l31) * 64;
#pragma unroll
            for (int st = 0; st < 4; ++st) {
                h8 a = *(const h8*)&Kc[rb + (((st * 2 + hi) ^ r7) << 3)];
                sc[s] = MFMA32(a, qf[st], sc[s]);
            }
        }
        __builtin_amdgcn_s_setprio(0);

#pragma unroll
        for (int s = 0; s < 2; ++s)
#pragma unroll
            for (int r = 0; r < 16; ++r)
                sc[s][r] = __builtin_amdgcn_exp2f(sc[s][r]);
#pragma unroll
        for (int r = 0; r < 16; ++r) { ls0 += sc[0][r]; ls1 += sc[1][r]; }

        __builtin_amdgcn_s_setprio(1);
#pragma unroll
        for (int ks = 0; ks < 4; ++ks) {
            const int s  = ks >> 1;
            const int e0 = (ks & 1) * 8;
            union { h2 h[4]; h8 v; } pf;
#pragma unroll
            for (int u2 = 0; u2 < 4; ++u2)
                pf.h[u2] = pk2(sc[s][e0 + 2 * u2], sc[s][e0 + 2 * u2 + 1]);
#pragma unroll
            for (int ds = 0; ds < 2; ++ds) {
                h8 av = *(const h8*)&Vc[(ds * 32 + l31) * 64 +
                                        (((ks * 2 + hi) ^ r7) << 3)];
                ov[ds] = MFMA32(av, pf.v, ov[ds]);
            }
        }
        __builtin_amdgcn_s_setprio(0);

        __syncthreads();
        cur ^= 1;
    }

    // partial row-sum for column q (= l31): own 32 keys + partner half
    float lsum = ls0 + ls1;
    lsum += __shfl_xor(lsum, 32);
    const int qrow = qt * QBLK + w * 32 + l31;
    if (hi == 0)
        l_ws[((size_t)(split * NB + b) * SL + qrow) * NH + hh] = lsum * 0x1p-12f;

    const float osc = 0x1p-12f;
    _Float16* orow = o_ws + ((size_t)split * NB * SL + (size_t)b * SL + qrow) * DM +
                     hh * DK;
#pragma unroll
    for (int ds = 0; ds < 2; ++ds) {
#pragma unroll
        for (int j = 0; j < 4; ++j) {
            const int d0 = ds * 32 + j * 8 + hi * 4;
            h2 w0 = pk2(ov[ds][4 * j] * osc,     ov[ds][4 * j + 1] * osc);
            h2 w1 = pk2(ov[ds][4 * j + 2] * osc, ov[ds][4 * j + 3] * osc);
            h4 val = {w0[0], w0[1], w1[0], w1[1]};
            *(h4*)&orow[d0] = val;
        }
    }
}

// ---------------------------------------------------------------------------
// Kernel 3: output projection with fused split-combine:
// A = (o0 + o1) * (1/(l0+l1)) per (row, head), reg-staged fp16; B = Wo fp32.
// ---------------------------------------------------------------------------
__global__ __launch_bounds__(256) void out_proj_kernel(
    const _Float16* __restrict__ o_ws, const float* __restrict__ l_ws,
    const float* __restrict__ Wo, const float* __restrict__ bo,
    float* __restrict__ out)
{
    const int bid = blockIdx.x;
    const int op  = (bid & 7) * 32 + (bid >> 3);
    const int nt  = op & 3;
    const int mt  = op >> 2;

    __shared__ __align__(16) _Float16 As[2][4096];
    __shared__ __align__(16) _Float16 Bs[2][4096];
    __shared__ float Linv[128][8];

    const int t   = threadIdx.x;
    const int w   = t >> 6;
    const int l   = t & 63;
    const int l31 = l & 31;
    const int hi  = l >> 5;
    const int mbase = mt * 128;
    const int nbase = nt * 128;
    const int wm = (w >> 1) * 64;
    const int wn = (w & 1) * 64;

    const size_t NSL = (size_t)NB * SL;

    // 1/(l0+l1) table: 128 rows x 8 heads
#pragma unroll
    for (int e = 0; e < 4; ++e) {
        const int idx = t * 4 + e;
        const int r = idx >> 3, h = idx & 7;
        const int m = mbase + r;
        const float l0 = l_ws[((size_t)m) * NH + h];
        const float l1 = l_ws[(NSL + (size_t)m) * NH + h];
        Linv[r][h] = 1.0f / (l0 + l1);
    }

    const int id0 = t, id1 = 256 + t;
    const int r0 = id0 >> 2, c0 = id0 & 3;
    const int r1 = id1 >> 2, c1 = id1 & 3;
    const int sl0 = (c0 ^ (r0 & 3)) * 8;
    const int sl1 = (c1 ^ (r1 & 3)) * 8;
    const _Float16* Ap00 = o_ws + (size_t)(mbase + r0) * DM + c0 * 8;
    const _Float16* Ap01 = Ap00 + NSL * DM;
    const _Float16* Ap10 = o_ws + (size_t)(mbase + r1) * DM + c1 * 8;
    const _Float16* Ap11 = Ap10 + NSL * DM;
    const float* Wp0 = Wo + (size_t)(nbase + r0) * DM + c0 * 8;
    const float* Wp1 = Wo + (size_t)(nbase + r1) * DM + c1 * 8;

    __syncthreads();  // Linv ready

    auto combine8 = [](h8 x, h8 y, float li) -> h8 {
        union { h2 h[4]; h8 v; } u;
#pragma unroll
        for (int e = 0; e < 4; ++e) {
            float a0 = ((float)x[2 * e]     + (float)y[2 * e])     * li;
            float a1 = ((float)x[2 * e + 1] + (float)y[2 * e + 1]) * li;
            u.h[e] = pk2(a0, a1);
        }
        return u.v;
    };

    f16v acc[2][2] = {};

    {
        h8 a00 = *(const h8*)Ap00, a01 = *(const h8*)Ap01;
        h8 a10 = *(const h8*)Ap10, a11 = *(const h8*)Ap11;
        float4 b00 = *(const float4*)(Wp0), b01 = *(const float4*)(Wp0 + 4);
        float4 b10 = *(const float4*)(Wp1), b11 = *(const float4*)(Wp1 + 4);
        *(h8*)&As[0][r0 * 32 + sl0] = combine8(a00, a01, Linv[r0][(c0 * 8) >> 6]);
        *(h8*)&As[0][r1 * 32 + sl1] = combine8(a10, a11, Linv[r1][(c1 * 8) >> 6]);
        *(h8*)&Bs[0][r0 * 32 + sl0] = cvt8(b00, b01);
        *(h8*)&Bs[0][r1 * 32 + sl1] = cvt8(b10, b11);
    }
    __syncthreads();

    int cur = 0;
    for (int step = 0; step < 16; ++step) {
        const int kn = (step + 1) * 32;
        const bool more = step + 1 < 16;
        h8 a00, a01, a10, a11;
        float4 b00, b01, b10, b11;
        float li0, li1;
        if (more) {
            a00 = *(const h8*)(Ap00 + kn); a01 = *(const h8*)(Ap01 + kn);
            a10 = *(const h8*)(Ap10 + kn); a11 = *(const h8*)(Ap11 + kn);
            b00 = *(const float4*)(Wp0 + kn); b01 = *(const float4*)(Wp0 + kn + 4);
            b10 = *(const float4*)(Wp1 + kn); b11 = *(const float4*)(Wp1 + kn + 4);
            li0 = Linv[r0][((kn + c0 * 8) >> 6) & 7];
            li1 = Linv[r1][((kn + c1 * 8) >> 6) & 7];
        }

        const _Float16* Ac = As[cur];
        const _Float16* Bc = Bs[cur];
        h8 af[2][2], bf[2][2];
#pragma unroll
        for (int ti = 0; ti < 2; ++ti)
#pragma unroll
            for (int s = 0; s < 2; ++s)
                af[ti][s] = *(const h8*)&Ac[(wm + ti * 32 + l31) * 32 +
                                            (((2 * s + hi) ^ (l31 & 3)) << 3)];
#pragma unroll
        for (int tj = 0; tj < 2; ++tj)
#pragma unroll
            for (int s = 0; s < 2; ++s)
                bf[tj][s] = *(const h8*)&Bc[(wn + tj * 32 + l31) * 32 +
                                            (((2 * s + hi) ^ (l31 & 3)) << 3)];
        __builtin_amdgcn_s_setprio(1);
#pragma unroll
        for (int ti = 0; ti < 2; ++ti)
#pragma unroll
            for (int tj = 0; tj < 2; ++tj)
#pragma unroll
                for (int s = 0; s < 2; ++s)
                    acc[ti][tj] = MFMA32(af[ti][s], bf[tj][s], acc[ti][tj]);
        __builtin_amdgcn_s_setprio(0);

        if (more) {
            const int nb2 = cur ^ 1;
            *(h8*)&As[nb2][r0 * 32 + sl0] = combine8(a00, a01, li0);
            *(h8*)&As[nb2][r1 * 32 + sl1] = combine8(a10, a11, li1);
            *(h8*)&Bs[nb2][r0 * 32 + sl0] = cvt8(b00, b01);
            *(h8*)&Bs[nb2][r1 * 32 + sl1] = cvt8(b10, b11);
        }
        __syncthreads();
        cur ^= 1;
    }

#pragma unroll
    for (int tj = 0; tj < 2; ++tj) {
        const int n = nbase + wn + tj * 32 + l31;
        const float bb = bo[n];
#pragma unroll
        for (int ti = 0; ti < 2; ++ti) {
#pragma unroll
            for (int j = 0; j < 4; ++j) {
#pragma unroll
                for (int c = 0; c < 4; ++c) {
                    const int m = mbase + wm + ti * 32 + 8 * j + 4 * hi + c;
                    out[(size_t)m * DM + n] = acc[ti][tj][4 * j + c] + bb;
                }
            }
        }
    }
}

// ---------------------------------------------------------------------------
extern "C" void kernel_launch(void* const* d_in, const int* in_sizes, int n_in,
                              void* d_out, int out_size, void* d_ws, size_t ws_size,
                              hipStream_t stream)
{
    const float* Q    = (const float*)d_in[0];
    const float* K    = (const float*)d_in[1];
    const float* V    = (const float*)d_in[2];
    const int*   mask = (const int*)d_in[3];
    const float* Wq   = (const float*)d_in[4];
    const float* bq   = (const float*)d_in[5];
    const float* Wk   = (const float*)d_in[6];
    const float* bk   = (const float*)d_in[7];
    const float* Wv   = (const float*)d_in[8];
    const float* bv   = (const float*)d_in[9];
    const float* Wo   = (const float*)d_in[10];
    const float* bo   = (const float*)d_in[11];
    float* out = (float*)d_out;

    _Float16* ws = (_Float16*)d_ws;
    const size_t per = (size_t)NB * NH * SL * DK;  // 4,194,304 halves
    _Float16* q_ws  = ws;
    _Float16* k_ws  = ws + per;
    _Float16* vT_ws = ws + 2 * per;
    _Float16* o_ws  = ws + 3 * per;                // 2 splits x per halves
    float*    l_ws  = (float*)(ws + 5 * per);      // 2*NB*SL*NH floats

    proj_qkv_kernel<<<dim3(768), 256, 0, stream>>>(
        Q, K, V, Wq, Wk, Wv, bq, bk, bv, q_ws, k_ws, vT_ws);

    attn_kernel<<<dim3(NB * NH, SL / QBLK, KSPL), 256, 0, stream>>>(
        q_ws, k_ws, vT_ws, mask, o_ws, l_ws);

    out_proj_kernel<<<dim3(256), 256, 0, stream>>>(o_ws, l_ws, Wo, bo, out);
}

// Round 8
// 128.744 us; speedup vs baseline: 1.3079x; 1.1073x over previous
//
#include <hip/hip_runtime.h>
#include <hip/hip_bf16.h>

typedef _Float16 h8 __attribute__((ext_vector_type(8)));
typedef _Float16 h4 __attribute__((ext_vector_type(4)));
typedef _Float16 h2 __attribute__((ext_vector_type(2)));
typedef float f2 __attribute__((ext_vector_type(2)));
typedef float f4 __attribute__((ext_vector_type(4)));
typedef float f16v __attribute__((ext_vector_type(16)));

#define MFMA32(a, b, c) __builtin_amdgcn_mfma_f32_32x32x16_f16(a, b, c, 0, 0, 0)

static constexpr int DM = 512;
static constexpr int SL = 4096;
static constexpr int NH = 8;
static constexpr int DK = 64;
static constexpr int NB = 2;

__device__ __forceinline__ h2 pk2(float a, float b) {
    return __builtin_bit_cast(h2, __builtin_amdgcn_cvt_pkrtz(a, b));
}
__device__ __forceinline__ h8 cvt8(float4 x, float4 y) {
    union { h2 h[4]; h8 v; } u;
    u.h[0] = pk2(x.x, x.y); u.h[1] = pk2(x.z, x.w);
    u.h[2] = pk2(y.x, y.y); u.h[3] = pk2(y.z, y.w);
    return u.v;
}

// ---------------------------------------------------------------------------
// Kernel 1: fused Q/K/V projections. 128x128 tile, BK=32, MFMA 32x32x16.
// (unchanged from round 7)
// ---------------------------------------------------------------------------
__global__ __launch_bounds__(256) void proj_qkv_kernel(
    const float* __restrict__ Qin, const float* __restrict__ Kin,
    const float* __restrict__ Vin,
    const float* __restrict__ Wq, const float* __restrict__ Wk,
    const float* __restrict__ Wv,
    const float* __restrict__ bq, const float* __restrict__ bk,
    const float* __restrict__ bv,
    _Float16* __restrict__ qo, _Float16* __restrict__ ko,
    _Float16* __restrict__ vTo)
{
    const int bid = blockIdx.x;
    const int op  = (bid & 7) * 96 + (bid >> 3);
    const int nt    = op & 3;
    const int panel = op >> 2;
    const int which = panel >> 6;
    const int mt    = panel & 63;

    const float* __restrict__ X    = which == 0 ? Qin : (which == 1 ? Kin : Vin);
    const float* __restrict__ W    = which == 0 ? Wq  : (which == 1 ? Wk  : Wv);
    const float* __restrict__ bias = which == 0 ? bq  : (which == 1 ? bk  : bv);

    __shared__ __align__(16) _Float16 As[2][4096];
    __shared__ __align__(16) _Float16 Bs[2][4096];
    __shared__ __align__(16) _Float16 Vtr[64][144];

    const int t   = threadIdx.x;
    const int w   = t >> 6;
    const int l   = t & 63;
    const int l31 = l & 31;
    const int hi  = l >> 5;
    const int mbase = mt * 128;
    const int nbase = nt * 128;
    const int wm = (w >> 1) * 64;
    const int wn = (w & 1) * 64;

    const int id0 = t, id1 = 256 + t;
    const int r0 = id0 >> 2, c0 = id0 & 3;
    const int r1 = id1 >> 2, c1 = id1 & 3;
    const int sl0 = (c0 ^ (r0 & 3)) * 8;
    const int sl1 = (c1 ^ (r1 & 3)) * 8;
    const float* Xp0 = X + (size_t)(mbase + r0) * DM + c0 * 8;
    const float* Xp1 = X + (size_t)(mbase + r1) * DM + c1 * 8;
    const float* Wp0 = W + (size_t)(nbase + r0) * DM + c0 * 8;
    const float* Wp1 = W + (size_t)(nbase + r1) * DM + c1 * 8;

    f16v acc[2][2] = {};

    {
        float4 a00 = *(const float4*)(Xp0), a01 = *(const float4*)(Xp0 + 4);
        float4 a10 = *(const float4*)(Xp1), a11 = *(const float4*)(Xp1 + 4);
        float4 b00 = *(const float4*)(Wp0), b01 = *(const float4*)(Wp0 + 4);
        float4 b10 = *(const float4*)(Wp1), b11 = *(const float4*)(Wp1 + 4);
        *(h8*)&As[0][r0 * 32 + sl0] = cvt8(a00, a01);
        *(h8*)&As[0][r1 * 32 + sl1] = cvt8(a10, a11);
        *(h8*)&Bs[0][r0 * 32 + sl0] = cvt8(b00, b01);
        *(h8*)&Bs[0][r1 * 32 + sl1] = cvt8(b10, b11);
    }
    __syncthreads();

    int cur = 0;
    for (int step = 0; step < 16; ++step) {
        const int kn = (step + 1) * 32;
        float4 a00, a01, a10, a11, b00, b01, b10, b11;
        const bool more = step + 1 < 16;
        if (more) {
            a00 = *(const float4*)(Xp0 + kn); a01 = *(const float4*)(Xp0 + kn + 4);
            a10 = *(const float4*)(Xp1 + kn); a11 = *(const float4*)(Xp1 + kn + 4);
            b00 = *(const float4*)(Wp0 + kn); b01 = *(const float4*)(Wp0 + kn + 4);
            b10 = *(const float4*)(Wp1 + kn); b11 = *(const float4*)(Wp1 + kn + 4);
        }

        const _Float16* Ac = As[cur];
        const _Float16* Bc = Bs[cur];
        h8 af[2][2], bf[2][2];
#pragma unroll
        for (int ti = 0; ti < 2; ++ti)
#pragma unroll
            for (int s = 0; s < 2; ++s)
                af[ti][s] = *(const h8*)&Ac[(wm + ti * 32 + l31) * 32 +
                                            (((2 * s + hi) ^ (l31 & 3)) << 3)];
#pragma unroll
        for (int tj = 0; tj < 2; ++tj)
#pragma unroll
            for (int s = 0; s < 2; ++s)
                bf[tj][s] = *(const h8*)&Bc[(wn + tj * 32 + l31) * 32 +
                                            (((2 * s + hi) ^ (l31 & 3)) << 3)];
        __builtin_amdgcn_s_setprio(1);
#pragma unroll
        for (int ti = 0; ti < 2; ++ti)
#pragma unroll
            for (int tj = 0; tj < 2; ++tj)
#pragma unroll
                for (int s = 0; s < 2; ++s)
                    acc[ti][tj] = MFMA32(af[ti][s], bf[tj][s], acc[ti][tj]);
        __builtin_amdgcn_s_setprio(0);

        if (more) {
            const int nb2 = cur ^ 1;
            *(h8*)&As[nb2][r0 * 32 + sl0] = cvt8(a00, a01);
            *(h8*)&As[nb2][r1 * 32 + sl1] = cvt8(a10, a11);
            *(h8*)&Bs[nb2][r0 * 32 + sl0] = cvt8(b00, b01);
            *(h8*)&Bs[nb2][r1 * 32 + sl1] = cvt8(b10, b11);
        }
        __syncthreads();
        cur ^= 1;
    }

    if (which < 2) {
        _Float16* dst = (which == 0) ? qo : ko;
#pragma unroll
        for (int tj = 0; tj < 2; ++tj) {
            const int n  = nbase + wn + tj * 32 + l31;
            const float bb = bias[n];
            const int hh = n >> 6;
            const int d  = n & 63;
#pragma unroll
            for (int ti = 0; ti < 2; ++ti) {
#pragma unroll
                for (int j = 0; j < 4; ++j) {
#pragma unroll
                    for (int c = 0; c < 4; ++c) {
                        const int m = mbase + wm + ti * 32 + 8 * j + 4 * hi + c;
                        const int bi = m >> 12;
                        const int s  = m & 4095;
                        dst[((size_t)(bi * NH + hh) * SL + s) * DK + d] =
                            (_Float16)(acc[ti][tj][4 * j + c] + bb);
                    }
                }
            }
        }
    } else {
        const int bi = mbase >> 12;
        const int s0 = mbase & 4095;
#pragma unroll
        for (int nh = 0; nh < 2; ++nh) {
            __syncthreads();
            if ((w & 1) == nh) {
#pragma unroll
                for (int tj = 0; tj < 2; ++tj) {
                    const int d = tj * 32 + l31;
                    const float bb = bias[nbase + nh * 64 + d];
#pragma unroll
                    for (int ti = 0; ti < 2; ++ti) {
#pragma unroll
                        for (int j = 0; j < 4; ++j) {
                            h2 x0 = pk2(acc[ti][tj][4 * j] + bb,
                                        acc[ti][tj][4 * j + 1] + bb);
                            h2 x1 = pk2(acc[ti][tj][4 * j + 2] + bb,
                                        acc[ti][tj][4 * j + 3] + bb);
                            h4 val = {x0[0], x0[1], x1[0], x1[1]};
                            *(h4*)&Vtr[d][wm + ti * 32 + 8 * j + 4 * hi] = val;
                        }
                    }
                }
            }
            __syncthreads();
            {
                const int d = t >> 2, part = t & 3;
                const int hh = nt * 2 + nh;
                _Float16* dstv = vTo + ((size_t)(bi * NH + hh) * DK + d) * SL +
                                 s0 + part * 32;
                h8 v0 = *(const h8*)&Vtr[d][part * 32];
                h8 v1 = *(const h8*)&Vtr[d][part * 32 + 8];
                h8 v2 = *(const h8*)&Vtr[d][part * 32 + 16];
                h8 v3 = *(const h8*)&Vtr[d][part * 32 + 24];
                *(h8*)(dstv)      = v0;
                *(h8*)(dstv + 8)  = v1;
                *(h8*)(dstv + 16) = v2;
                *(h8*)(dstv + 24) = v3;
            }
        }
    }
}

// ---------------------------------------------------------------------------
// Kernel 2: flash attention. 512 threads / 8 waves per block (QBLK=256) so
// 16 waves/CU even at 2 blocks/CU. K-split=2, KVBLK=64, LDS 40KB.
// ---------------------------------------------------------------------------
static constexpr int QBLK  = 256;
static constexpr int KSPL  = 2;
static constexpr int KHALF = SL / KSPL;   // 2048
static constexpr int NTS   = KHALF / 64;  // 32

__device__ __forceinline__ void stage_tiles(
    _Float16* Ktb, _Float16* Vtb,
    const _Float16* kbh, const _Float16* vbh, int kb, int t)
{
    const int w = t >> 6;
    const char* ksrc = (const char*)(kbh + (size_t)kb * DK);
    {
        const int c  = t;                       // 16B chunk 0..511
        const int kr = c >> 3;
        const int sl = c & 7;
        const int srow = (kr & ~12) | ((kr & 4) << 1) | ((kr & 8) >> 1);
        const int cs = srow * 8 + (sl ^ (kr & 7));
        char* dst = (char*)Ktb + (size_t)w * 1024;   // wave-uniform
        __builtin_amdgcn_global_load_lds(
            (const __attribute__((address_space(1))) void*)(ksrc + (size_t)cs * 16),
            (__attribute__((address_space(3))) void*)dst, 16, 0, 0);
    }
    {
        const int c  = t;
        const int d  = c >> 3;
        const int cs = (c & 7) ^ (d & 7);
        const _Float16* src = vbh + (size_t)d * SL + kb + cs * 8;
        char* dst = (char*)Vtb + (size_t)w * 1024;
        __builtin_amdgcn_global_load_lds(
            (const __attribute__((address_space(1))) void*)src,
            (__attribute__((address_space(3))) void*)dst, 16, 0, 0);
    }
}

__global__ __launch_bounds__(512, 4) void attn_kernel(
    const _Float16* __restrict__ qg, const _Float16* __restrict__ kg,
    const _Float16* __restrict__ vTg, const int* __restrict__ mask,
    _Float16* __restrict__ o_ws, float* __restrict__ l_ws)
{
    const int t   = threadIdx.x;
    const int w   = t >> 6;
    const int l   = t & 63;
    const int l31 = l & 31;
    const int hi  = l >> 5;
    const int r7  = l31 & 7;
    const int hh  = blockIdx.x & 7;
    const int b   = blockIdx.x >> 3;
    const int qt  = blockIdx.y;
    const int split = blockIdx.z;
    const int koff  = split * KHALF;

    const _Float16* qbh = qg  + (size_t)(b * NH + hh) * SL * DK;
    const _Float16* kbh = kg  + (size_t)(b * NH + hh) * SL * DK;
    const _Float16* vbh = vTg + (size_t)(b * NH + hh) * DK * SL;
    const int* mrow = mask + b * SL;

    __shared__ __align__(16) _Float16 Kt[2][4096];
    __shared__ __align__(16) _Float16 Vt[2][4096];
    __shared__ __align__(16) float bias_tab[KHALF];   // 8 KB

    // mask -> f32 bias table for this key half (4 entries/thread, 512 thr)
    {
        int4 v = *(const int4*)&mrow[koff + t * 4];
        f4 bv;
        bv[0] = v.x ? 0.f : -1e38f; bv[1] = v.y ? 0.f : -1e38f;
        bv[2] = v.z ? 0.f : -1e38f; bv[3] = v.w ? 0.f : -1e38f;
        *(f4*)&bias_tab[t * 4] = bv;
    }

    const _Float16 sch = (_Float16)(0.125f * 1.44269504089f);
    const h8 sc8 = {sch, sch, sch, sch, sch, sch, sch, sch};
    h8 qf[4];
    {
        const _Float16* qp = qbh + (size_t)(qt * QBLK + w * 32 + l31) * DK + hi * 8;
#pragma unroll
        for (int st = 0; st < 4; ++st)
            qf[st] = *(const h8*)(qp + st * 16) * sc8;
    }

    stage_tiles(Kt[0], Vt[0], kbh, vbh, koff, t);
    __syncthreads();

    f16v ov[2] = {};
    float ls0 = 0.f, ls1 = 0.f;

    int cur = 0;
    for (int kt = 0; kt < NTS; ++kt) {
        const int kb = koff + kt * 64;
        if (kt + 1 < NTS)
            stage_tiles(Kt[cur ^ 1], Vt[cur ^ 1], kbh, vbh, kb + 64, t);

        const _Float16* Kc = Kt[cur];
        const _Float16* Vc = Vt[cur];
        const int lb = kt * 64;   // local bias base

        f16v sc[2];
#pragma unroll
        for (int s = 0; s < 2; ++s) {
            union { f2 q[8]; f16v v; } u;
#pragma unroll
            for (int j = 0; j < 4; ++j) {
                const int base = lb + s * 32 + ((j >> 1) << 4) +
                                 ((j & 1) << 2) + (hi << 3);
                u.q[2 * j]     = *(const f2*)&bias_tab[base];
                u.q[2 * j + 1] = *(const f2*)&bias_tab[base + 2];
            }
            sc[s] = u.v;
        }

        __builtin_amdgcn_s_setprio(1);
#pragma unroll
        for (int s = 0; s < 2; ++s) {
            const int rb = (s * 32 + l31) * 64;
#pragma unroll
            for (int st = 0; st < 4; ++st) {
                h8 a = *(const h8*)&Kc[rb + (((st * 2 + hi) ^ r7) << 3)];
                sc[s] = MFMA32(a, qf[st], sc[s]);
            }
        }
        __builtin_amdgcn_s_setprio(0);

#pragma unroll
        for (int s = 0; s < 2; ++s)
#pragma unroll
            for (int r = 0; r < 16; ++r)
                sc[s][r] = __builtin_amdgcn_exp2f(sc[s][r]);
#pragma unroll
        for (int r = 0; r < 16; ++r) { ls0 += sc[0][r]; ls1 += sc[1][r]; }

        __builtin_amdgcn_s_setprio(1);
#pragma unroll
        for (int ks = 0; ks < 4; ++ks) {
            const int s  = ks >> 1;
            const int e0 = (ks & 1) * 8;
            union { h2 h[4]; h8 v; } pf;
#pragma unroll
            for (int u2 = 0; u2 < 4; ++u2)
                pf.h[u2] = pk2(sc[s][e0 + 2 * u2], sc[s][e0 + 2 * u2 + 1]);
#pragma unroll
            for (int ds = 0; ds < 2; ++ds) {
                h8 av = *(const h8*)&Vc[(ds * 32 + l31) * 64 +
                                        (((ks * 2 + hi) ^ r7) << 3)];
                ov[ds] = MFMA32(av, pf.v, ov[ds]);
            }
        }
        __builtin_amdgcn_s_setprio(0);

        __syncthreads();
        cur ^= 1;
    }

    // partial row-sum for column q (= l31): own 32 keys + partner half
    float lsum = ls0 + ls1;
    lsum += __shfl_xor(lsum, 32);
    const int qrow = qt * QBLK + w * 32 + l31;
    if (hi == 0)
        l_ws[((size_t)(split * NB + b) * SL + qrow) * NH + hh] = lsum * 0x1p-12f;

    const float osc = 0x1p-12f;
    _Float16* orow = o_ws + ((size_t)split * NB * SL + (size_t)b * SL + qrow) * DM +
                     hh * DK;
#pragma unroll
    for (int ds = 0; ds < 2; ++ds) {
#pragma unroll
        for (int j = 0; j < 4; ++j) {
            const int d0 = ds * 32 + j * 8 + hi * 4;
            h2 w0 = pk2(ov[ds][4 * j] * osc,     ov[ds][4 * j + 1] * osc);
            h2 w1 = pk2(ov[ds][4 * j + 2] * osc, ov[ds][4 * j + 3] * osc);
            h4 val = {w0[0], w0[1], w1[0], w1[1]};
            *(h4*)&orow[d0] = val;
        }
    }
}

// ---------------------------------------------------------------------------
// Kernel 3: output projection with fused split-combine.
// (unchanged from round 7)
// ---------------------------------------------------------------------------
__global__ __launch_bounds__(256) void out_proj_kernel(
    const _Float16* __restrict__ o_ws, const float* __restrict__ l_ws,
    const float* __restrict__ Wo, const float* __restrict__ bo,
    float* __restrict__ out)
{
    const int bid = blockIdx.x;
    const int op  = (bid & 7) * 32 + (bid >> 3);
    const int nt  = op & 3;
    const int mt  = op >> 2;

    __shared__ __align__(16) _Float16 As[2][4096];
    __shared__ __align__(16) _Float16 Bs[2][4096];
    __shared__ float Linv[128][8];

    const int t   = threadIdx.x;
    const int w   = t >> 6;
    const int l   = t & 63;
    const int l31 = l & 31;
    const int hi  = l >> 5;
    const int mbase = mt * 128;
    const int nbase = nt * 128;
    const int wm = (w >> 1) * 64;
    const int wn = (w & 1) * 64;

    const size_t NSL = (size_t)NB * SL;

#pragma unroll
    for (int e = 0; e < 4; ++e) {
        const int idx = t * 4 + e;
        const int r = idx >> 3, h = idx & 7;
        const int m = mbase + r;
        const float l0 = l_ws[((size_t)m) * NH + h];
        const float l1 = l_ws[(NSL + (size_t)m) * NH + h];
        Linv[r][h] = 1.0f / (l0 + l1);
    }

    const int id0 = t, id1 = 256 + t;
    const int r0 = id0 >> 2, c0 = id0 & 3;
    const int r1 = id1 >> 2, c1 = id1 & 3;
    const int sl0 = (c0 ^ (r0 & 3)) * 8;
    const int sl1 = (c1 ^ (r1 & 3)) * 8;
    const _Float16* Ap00 = o_ws + (size_t)(mbase + r0) * DM + c0 * 8;
    const _Float16* Ap01 = Ap00 + NSL * DM;
    const _Float16* Ap10 = o_ws + (size_t)(mbase + r1) * DM + c1 * 8;
    const _Float16* Ap11 = Ap10 + NSL * DM;
    const float* Wp0 = Wo + (size_t)(nbase + r0) * DM + c0 * 8;
    const float* Wp1 = Wo + (size_t)(nbase + r1) * DM + c1 * 8;

    __syncthreads();  // Linv ready

    auto combine8 = [](h8 x, h8 y, float li) -> h8 {
        union { h2 h[4]; h8 v; } u;
#pragma unroll
        for (int e = 0; e < 4; ++e) {
            float a0 = ((float)x[2 * e]     + (float)y[2 * e])     * li;
            float a1 = ((float)x[2 * e + 1] + (float)y[2 * e + 1]) * li;
            u.h[e] = pk2(a0, a1);
        }
        return u.v;
    };

    f16v acc[2][2] = {};

    {
        h8 a00 = *(const h8*)Ap00, a01 = *(const h8*)Ap01;
        h8 a10 = *(const h8*)Ap10, a11 = *(const h8*)Ap11;
        float4 b00 = *(const float4*)(Wp0), b01 = *(const float4*)(Wp0 + 4);
        float4 b10 = *(const float4*)(Wp1), b11 = *(const float4*)(Wp1 + 4);
        *(h8*)&As[0][r0 * 32 + sl0] = combine8(a00, a01, Linv[r0][(c0 * 8) >> 6]);
        *(h8*)&As[0][r1 * 32 + sl1] = combine8(a10, a11, Linv[r1][(c1 * 8) >> 6]);
        *(h8*)&Bs[0][r0 * 32 + sl0] = cvt8(b00, b01);
        *(h8*)&Bs[0][r1 * 32 + sl1] = cvt8(b10, b11);
    }
    __syncthreads();

    int cur = 0;
    for (int step = 0; step < 16; ++step) {
        const int kn = (step + 1) * 32;
        const bool more = step + 1 < 16;
        h8 a00, a01, a10, a11;
        float4 b00, b01, b10, b11;
        float li0, li1;
        if (more) {
            a00 = *(const h8*)(Ap00 + kn); a01 = *(const h8*)(Ap01 + kn);
            a10 = *(const h8*)(Ap10 + kn); a11 = *(const h8*)(Ap11 + kn);
            b00 = *(const float4*)(Wp0 + kn); b01 = *(const float4*)(Wp0 + kn + 4);
            b10 = *(const float4*)(Wp1 + kn); b11 = *(const float4*)(Wp1 + kn + 4);
            li0 = Linv[r0][((kn + c0 * 8) >> 6) & 7];
            li1 = Linv[r1][((kn + c1 * 8) >> 6) & 7];
        }

        const _Float16* Ac = As[cur];
        const _Float16* Bc = Bs[cur];
        h8 af[2][2], bf[2][2];
#pragma unroll
        for (int ti = 0; ti < 2; ++ti)
#pragma unroll
            for (int s = 0; s < 2; ++s)
                af[ti][s] = *(const h8*)&Ac[(wm + ti * 32 + l31) * 32 +
                                            (((2 * s + hi) ^ (l31 & 3)) << 3)];
#pragma unroll
        for (int tj = 0; tj < 2; ++tj)
#pragma unroll
            for (int s = 0; s < 2; ++s)
                bf[tj][s] = *(const h8*)&Bc[(wn + tj * 32 + l31) * 32 +
                                            (((2 * s + hi) ^ (l31 & 3)) << 3)];
        __builtin_amdgcn_s_setprio(1);
#pragma unroll
        for (int ti = 0; ti < 2; ++ti)
#pragma unroll
            for (int tj = 0; tj < 2; ++tj)
#pragma unroll
                for (int s = 0; s < 2; ++s)
                    acc[ti][tj] = MFMA32(af[ti][s], bf[tj][s], acc[ti][tj]);
        __builtin_amdgcn_s_setprio(0);

        if (more) {
            const int nb2 = cur ^ 1;
            *(h8*)&As[nb2][r0 * 32 + sl0] = combine8(a00, a01, li0);
            *(h8*)&As[nb2][r1 * 32 + sl1] = combine8(a10, a11, li1);
            *(h8*)&Bs[nb2][r0 * 32 + sl0] = cvt8(b00, b01);
            *(h8*)&Bs[nb2][r1 * 32 + sl1] = cvt8(b10, b11);
        }
        __syncthreads();
        cur ^= 1;
    }

#pragma unroll
    for (int tj = 0; tj < 2; ++tj) {
        const int n = nbase + wn + tj * 32 + l31;
        const float bb = bo[n];
#pragma unroll
        for (int ti = 0; ti < 2; ++ti) {
#pragma unroll
            for (int j = 0; j < 4; ++j) {
#pragma unroll
                for (int c = 0; c < 4; ++c) {
                    const int m = mbase + wm + ti * 32 + 8 * j + 4 * hi + c;
                    out[(size_t)m * DM + n] = acc[ti][tj][4 * j + c] + bb;
                }
            }
        }
    }
}

// ---------------------------------------------------------------------------
extern "C" void kernel_launch(void* const* d_in, const int* in_sizes, int n_in,
                              void* d_out, int out_size, void* d_ws, size_t ws_size,
                              hipStream_t stream)
{
    const float* Q    = (const float*)d_in[0];
    const float* K    = (const float*)d_in[1];
    const float* V    = (const float*)d_in[2];
    const int*   mask = (const int*)d_in[3];
    const float* Wq   = (const float*)d_in[4];
    const float* bq   = (const float*)d_in[5];
    const float* Wk   = (const float*)d_in[6];
    const float* bk   = (const float*)d_in[7];
    const float* Wv   = (const float*)d_in[8];
    const float* bv   = (const float*)d_in[9];
    const float* Wo   = (const float*)d_in[10];
    const float* bo   = (const float*)d_in[11];
    float* out = (float*)d_out;

    _Float16* ws = (_Float16*)d_ws;
    const size_t per = (size_t)NB * NH * SL * DK;  // 4,194,304 halves
    _Float16* q_ws  = ws;
    _Float16* k_ws  = ws + per;
    _Float16* vT_ws = ws + 2 * per;
    _Float16* o_ws  = ws + 3 * per;                // 2 splits x per halves
    float*    l_ws  = (float*)(ws + 5 * per);      // 2*NB*SL*NH floats

    proj_qkv_kernel<<<dim3(768), 256, 0, stream>>>(
        Q, K, V, Wq, Wk, Wv, bq, bk, bv, q_ws, k_ws, vT_ws);

    attn_kernel<<<dim3(NB * NH, SL / QBLK, KSPL), 512, 0, stream>>>(
        q_ws, k_ws, vT_ws, mask, o_ws, l_ws);

    out_proj_kernel<<<dim3(256), 256, 0, stream>>>(o_ws, l_ws, Wo, bo, out);
}